// Round 19
// baseline (80.753 us; speedup 1.0000x reference)
//
#include <hip/hip_runtime.h>
#include <hip/hip_bf16.h>

typedef __hip_bfloat16 bf16;
typedef __attribute__((ext_vector_type(8))) short short8;
typedef __attribute__((ext_vector_type(4))) short short4v;
typedef __attribute__((ext_vector_type(4))) float f32x4;

#define N_      4
#define R_      64
#define HD_     16
#define H_      48
#define W_      48
#define P_      (H_ * W_)      // 2304
#define HP_     50
#define PP_     (HP_ * HP_)    // 2500
#define HK_     46
#define DK_     (HK_ * HK_)    // 2116
#define CG_     256
#define KPAD_   2144
#define WCONV_  516096
#define WGATE_  16384
#define NTILE_  134
#define TPW_    34
#define LOG2E_  1.44269504f
#define QTOT_   (16 * 2304 * 16)
#define KTOT_   (16 * KPAD_ * 16)
#define VTOT_   (16 * NTILE_ * 256)   // tile-blocked V: [ngi][tile][c][16]
#define GTH_    196608          // 768 * 256
#define ZXH_    (N_ * 196 * 16)
#define ZKB_    (16 * 28 * 2)
#define ZVB_    1024            // zero tiles 132,133 of Vb (short8 granularity)
#define ZTOT_   (ZXH_ + ZKB_ + ZVB_)
#define AWP_    18432           // wt shorts per (mg,wid): 9 taps * 4 cb * 512

// LDS B-tile: 150 rows x 128 shorts (256B), XOR-swizzled (T2):
//   physical colshorts = logical ^ ((row & 7) << 3)
// -> b128 reads stay 16B-aligned; 16-lane column reads hit 8 bank-groups
//    (2-way = free) instead of BPAD136's 8-way conflict (r10: 2.3M conflicts).
#define BROW_   128
__device__ __forceinline__ int bswz(int row, int colshorts) {
    return row * BROW_ + (colshorts ^ ((row & 7) << 3));
}

__device__ __forceinline__ float sigmoidf_(float x) { return 1.f / (1.f + __expf(-x)); }
__device__ __forceinline__ float tanh_fast(float x) {
    float e = __expf(-2.f * fabsf(x));
    float t = (1.f - e) / (1.f + e);
    return copysignf(t, x);
}
__device__ __forceinline__ float ldrt(const void* p, size_t i, bool bf) {
    return bf ? __bfloat162float(((const bf16*)p)[i]) : ((const float*)p)[i];
}
__device__ __forceinline__ unsigned short f2b(float f) {
    bf16 b = __float2bfloat16(f);
    return *reinterpret_cast<unsigned short*>(&b);
}

struct MP {
    const void* x_in; const void* h; const void* c_in;
    const void* W_x;  const void* b_x; const void* b_v;
    const void* bi; const void* bf; const void* bg; const void* bo;
    const void* wsrc[11];
    unsigned short *xh_t, *wt, *Qb, *Kb, *Vb, *a_bt;
    float* C;
    void* h_out;
};

// ---------------------------------------------------------------------------
// dtype detect: every thread reads W_x's first 64 words (L2 broadcast, cheap).
// ---------------------------------------------------------------------------
__device__ __forceinline__ bool detect_bf(const void* W_x) {
    const unsigned* wx = (const unsigned*)W_x;
    int votes = 0;
    #pragma unroll 8
    for (int i = 0; i < 64; i++) {
        unsigned e = (wx[i] >> 7) & 0xFFu;
        votes += (e >= 100u && e <= 134u) ? 1 : 0;
    }
    return votes >= 48;
}

// ---------------------------------------------------------------------------
// S1a: proj_x 1x1 conv (2 co x 2 p per item, 147456 items) -> xh_t bf16.
// ---------------------------------------------------------------------------
__device__ void s1_build_x(int idx, bool isbf, const MP& P) {
    int pp  = idx % 1152;
    int cog = (idx / 1152) & 31;
    int n   = idx / (1152 * 32);
    int p0 = pp * 2;
    int co0 = cog * 2;

    float acc[2][2];
    #pragma unroll
    for (int j = 0; j < 2; j++) { float b = ldrt(P.b_x, co0 + j, isbf); acc[j][0] = b; acc[j][1] = b; }

    if (isbf) {
        const unsigned* xw = (const unsigned*)P.x_in;
        const unsigned* ww = (const unsigned*)P.W_x;
        size_t xbase = ((size_t)n * 128 * P_ + p0) >> 1;
        #pragma unroll 4
        for (int ci = 0; ci < 128; ci += 2) {
            unsigned xa  = xw[xbase + (size_t)ci * (P_ / 2)];
            unsigned xb2 = xw[xbase + (size_t)(ci + 1) * (P_ / 2)];
            float x0a = __uint_as_float(xa << 16),  x1a = __uint_as_float(xa & 0xffff0000u);
            float x0b = __uint_as_float(xb2 << 16), x1b = __uint_as_float(xb2 & 0xffff0000u);
            #pragma unroll
            for (int j = 0; j < 2; j++) {
                unsigned wp2 = ww[((co0 + j) * 128 + ci) >> 1];
                float w0 = __uint_as_float(wp2 << 16);
                float w1 = __uint_as_float(wp2 & 0xffff0000u);
                acc[j][0] += w0 * x0a + w1 * x0b;
                acc[j][1] += w0 * x1a + w1 * x1b;
            }
        }
    } else {
        const float* xf = (const float*)P.x_in;
        const float* wf = (const float*)P.W_x;
        size_t xb = (size_t)n * 128 * P_ + p0;
        #pragma unroll 4
        for (int ci = 0; ci < 128; ci++) {
            float x0 = xf[xb + (size_t)ci * P_];
            float x1 = xf[xb + (size_t)ci * P_ + 1];
            #pragma unroll
            for (int j = 0; j < 2; j++) {
                float w = wf[(co0 + j) * 128 + ci];
                acc[j][0] += w * x0;
                acc[j][1] += w * x1;
            }
        }
    }
    #pragma unroll
    for (int pi = 0; pi < 2; pi++) {
        int p = p0 + pi;
        int py = p / W_ + 1, px = p % W_ + 1;
        unsigned pk = (unsigned)f2b(acc[0][pi]) | ((unsigned)f2b(acc[1][pi]) << 16);
        *reinterpret_cast<unsigned*>(P.xh_t + ((size_t)n * PP_ + py * HP_ + px) * 128 + co0) = pk;
    }
}

// S1b: h -> xh_t channels 64..127 (8 ch x 2 px per item, 36864 items).
__device__ void s1_copy_h(int idx, bool isbf, const MP& P) {
    int pp = idx % 1152;
    int cgp = (idx / 1152) & 7;
    int n  = idx / (1152 * 8);
    int p0 = pp * 2;
    int py = p0 / W_ + 1, px = p0 % W_ + 1;
    short8 v0, v1;
    if (isbf) {
        const unsigned* hw = (const unsigned*)P.h;
        #pragma unroll
        for (int j = 0; j < 8; j++) {
            unsigned pr = hw[(((size_t)n * R_ + cgp * 8 + j) * P_ + p0) >> 1];
            v0[j] = (short)(pr & 0xffffu);
            v1[j] = (short)(pr >> 16);
        }
    } else {
        #pragma unroll
        for (int j = 0; j < 8; j++) {
            size_t b = ((size_t)n * R_ + cgp * 8 + j) * P_ + p0;
            v0[j] = (short)f2b(ldrt(P.h, b, false));
            v1[j] = (short)f2b(ldrt(P.h, b + 1, false));
        }
    }
    unsigned short* dst = P.xh_t + ((size_t)n * PP_ + py * HP_ + px) * 128 + 64 + cgp * 8;
    *reinterpret_cast<short8*>(dst) = v0;
    *reinterpret_cast<short8*>(dst + 128) = v1;
}

// S1c: weight repack. Conv region uses FRAGMENT-MAJOR layout
//   wt[(mg*4+wid)*AWP_ + tap*2048 + cb*512 + (l15*4+kq)*8 + j]
//   = W[set=mg][co=wid*16+l15][ci=cb*32+kq*8+j][tap]
// so each A-frag load in s2 is one contiguous 1KB wave transaction.
__device__ void s1_wt(int idx, bool isbf, const MP& P) {
    if (idx < WCONV_) {
        int j   = idx & 7;
        int kq  = (idx >> 3) & 3;
        int l15 = (idx >> 5) & 15;
        int cb  = (idx >> 9) & 3;
        int tap = (idx >> 11) % 9;
        int wp  = idx / AWP_;
        int mg  = wp >> 2, wid = wp & 3;
        int co  = wid * 16 + l15;
        int ci  = cb * 32 + kq * 8 + j;
        P.wt[idx] = f2b(ldrt(P.wsrc[mg], (size_t)(co * 128 + ci) * 9 + tap, isbf));
    } else if (idx < WCONV_ + WGATE_) {
        int j  = idx - WCONV_;
        int ca = j & 63;
        int m  = j >> 6;
        int gate = m >> 6, r = m & 63;
        P.wt[idx] = f2b(ldrt(P.wsrc[7 + gate], r * 64 + ca, isbf));
    }
}

// S1d: zero pad item. Vb is tile-blocked: zero tiles 132/133 fully
// (conv later overwrites real keys 2112..2115; prep strictly precedes conv).
__device__ void s1_zero(int idx, const MP& P) {
    const short8 z8 = {0, 0, 0, 0, 0, 0, 0, 0};
    if (idx < ZXH_) {
        int cig = idx & 15;
        int pi  = (idx >> 4) % 196;
        int n   = idx / (196 * 16);
        int pp;
        if (pi < 50)       pp = pi;
        else if (pi < 100) pp = 49 * 50 + (pi - 50);
        else if (pi < 148) pp = (pi - 100 + 1) * 50;
        else               pp = (pi - 148 + 1) * 50 + 49;
        *reinterpret_cast<short8*>(P.xh_t + ((size_t)n * PP_ + pp) * 128 + cig * 8) = z8;
        return;
    }
    int j = idx - ZXH_;
    if (j < ZKB_) {
        int hh  = j & 1;
        int key = ((j >> 1) % 28) + DK_;
        int ngi = j / (28 * 2);
        *reinterpret_cast<short8*>(P.Kb + ((size_t)ngi * KPAD_ + key) * 16 + hh * 8) = z8;
        return;
    }
    j -= ZKB_;
    if (j < ZVB_) {
        int h8  = j & 1;
        int c   = (j >> 1) & 15;
        int tl  = (j >> 5) & 1;      // tile 132 or 133
        int ngi = j >> 6;
        *reinterpret_cast<short8*>(
            P.Vb + (((size_t)ngi * NTILE_ + 132 + tl) * 16 + c) * 16 + h8 * 8) = z8;
    }
}

__device__ void s1_all(int gid, bool isbf, const MP& P) {
    if (gid < 147456) s1_build_x(gid, isbf, P);
    if (gid < 36864)  s1_copy_h(gid, isbf, P);
    for (int i = gid; i < WCONV_ + WGATE_; i += GTH_) s1_wt(i, isbf, P);
    if (gid < ZTOT_)  s1_zero(gid, P);
}

// ---------------------------------------------------------------------------
// S2: seven 3x3 convs as one implicit GEMM (paired m-frags, A prefetch,
//     fragment-major wt; XOR-swizzled LDS B-tile).
// ---------------------------------------------------------------------------
__device__ void s2_conv(int bid, int tid, unsigned short* Bs, bool isbf, const MP& P) {
    int wid  = tid >> 6;
    int lane = tid & 63;
    int pb = bid & 3;
    int y  = (bid >> 2) % 48;
    int n  = bid / 192;
    int l15 = lane & 15;
    int kq  = lane >> 4;

    const unsigned short* src = P.xh_t + (size_t)n * PP_ * 128 + (size_t)y * HP_ * 128;
    for (int i = tid; i < 2400; i += 256) {
        int r  = i / 800, e8 = i % 800;
        int px = e8 >> 4, cig = e8 & 15;
        int row = r * HP_ + px;
        short8 v = *reinterpret_cast<const short8*>(src + r * 6400 + e8 * 8);
        *reinterpret_cast<short8*>(Bs + bswz(row, cig * 8)) = v;
    }
    __syncthreads();

    int mg0 = pb * 2;
    int mg1 = min(pb * 2 + 1, 6);
    int lofs = (l15 * 4 + kq) * 8;
    const unsigned short* Ab0 = P.wt + (size_t)(mg0 * 4 + wid) * AWP_ + lofs;
    const unsigned short* Ab1 = P.wt + (size_t)(mg1 * 4 + wid) * AWP_ + lofs;

    f32x4 acc[2][3] = {{f32x4{0,0,0,0}, f32x4{0,0,0,0}, f32x4{0,0,0,0}},
                       {f32x4{0,0,0,0}, f32x4{0,0,0,0}, f32x4{0,0,0,0}}};

    short8 Acur[2][4], Anext[2][4];
    #pragma unroll
    for (int cb = 0; cb < 4; cb++) {
        Acur[0][cb] = *reinterpret_cast<const short8*>(Ab0 + cb * 512);
        Acur[1][cb] = *reinterpret_cast<const short8*>(Ab1 + cb * 512);
    }

    #pragma unroll
    for (int tap = 0; tap < 9; tap++) {
        if (tap < 8) {
            #pragma unroll
            for (int cb = 0; cb < 4; cb++) {
                Anext[0][cb] = *reinterpret_cast<const short8*>(Ab0 + (tap + 1) * 2048 + cb * 512);
                Anext[1][cb] = *reinterpret_cast<const short8*>(Ab1 + (tap + 1) * 2048 + cb * 512);
            }
        }
        int r = tap / 3, c = tap % 3;
        #pragma unroll
        for (int cb = 0; cb < 4; cb++) {
            short8 b8[3];
            #pragma unroll
            for (int nf = 0; nf < 3; nf++) {
                int row = r * HP_ + c + nf * 16 + l15;
                b8[nf] = *reinterpret_cast<const short8*>(
                    Bs + bswz(row, cb * 32 + kq * 8));
            }
            #pragma unroll
            for (int nf = 0; nf < 3; nf++) {
                acc[0][nf] = __builtin_amdgcn_mfma_f32_16x16x32_bf16(Acur[0][cb], b8[nf], acc[0][nf], 0, 0, 0);
                acc[1][nf] = __builtin_amdgcn_mfma_f32_16x16x32_bf16(Acur[1][cb], b8[nf], acc[1][nf], 0, 0, 0);
            }
        }
        #pragma unroll
        for (int cb = 0; cb < 4; cb++) {
            Acur[0][cb] = Anext[0][cb];
            Acur[1][cb] = Anext[1][cb];
        }
    }

    #pragma unroll
    for (int f = 0; f < 2; f++) {
        if (pb == 3 && f == 1) break;
        int mg = pb * 2 + f;
        if (mg >= 3) {
            #pragma unroll
            for (int nf = 0; nf < 3; nf++) {
                int p = y * 48 + nf * 16 + l15;
                #pragma unroll
                for (int reg = 0; reg < 4; reg++) {
                    int row = (mg - 3) * 64 + wid * 16 + kq * 4 + reg;
                    P.C[((size_t)n * CG_ + row) * P_ + p] = acc[f][nf][reg];
                }
            }
        } else {
            int g = wid;
            int ngi = n * 4 + g;
            #pragma unroll
            for (int nf = 0; nf < 3; nf++) {
                int x = nf * 16 + l15;
                int p = y * 48 + x;
                if (mg == 0) {
                    short4v q4;
                    #pragma unroll
                    for (int reg = 0; reg < 4; reg++) q4[reg] = (short)f2b(acc[f][nf][reg] * LOG2E_);
                    *reinterpret_cast<short4v*>(P.Qb + ((size_t)ngi * 2304 + p) * 16 + kq * 4) = q4;
                } else if ((unsigned)(x - 1) < 46u && (unsigned)(y - 1) < 46u) {
                    int key = (y - 1) * 46 + (x - 1);
                    if (mg == 1) {
                        short4v k4;
                        #pragma unroll
                        for (int reg = 0; reg < 4; reg++) k4[reg] = (short)f2b(acc[f][nf][reg]);
                        *reinterpret_cast<short4v*>(P.Kb + ((size_t)ngi * KPAD_ + key) * 16 + kq * 4) = k4;
                    } else {
                        int tile = key >> 4, kw = key & 15;
                        #pragma unroll
                        for (int reg = 0; reg < 4; reg++) {
                            int c2 = kq * 4 + reg;
                            P.Vb[(((size_t)ngi * NTILE_ + tile) * 16 + c2) * 16 + kw] =
                                f2b(acc[f][nf][reg] + ldrt(P.b_v, g * 16 + c2, isbf));
                        }
                    }
                }
            }
        }
    }
}

// ---------------------------------------------------------------------------
// S3: MFMA flash attention; 768 units = (q-triple 0..47, ng 0..15).
//     3 q-tiles per wave, 4-way key split, 1-deep K/V prefetch.
// ---------------------------------------------------------------------------
__device__ void s3_attn(int bid, int tid, float (*red)[64][15], const MP& P) {
    int wid  = tid >> 6;
    int lane = tid & 63;
    int ng = bid & 15;
    int q3 = bid >> 4;             // 0..47
    int qt0 = q3 * 3;
    int l15 = lane & 15;
    int g4  = lane >> 4;

    short4v qf[3];
    #pragma unroll
    for (int j = 0; j < 3; j++)
        qf[j] = *reinterpret_cast<const short4v*>(
            P.Qb + ((size_t)ng * 2304 + (qt0 + j) * 16 + l15) * 16 + g4 * 4);
    const unsigned short* Kp = P.Kb + ((size_t)ng * KPAD_ + l15) * 16 + g4 * 4;
    const unsigned short* Vp = P.Vb + (size_t)ng * NTILE_ * 256 + l15 * 16 + g4 * 4;

    f32x4 aA[3] = {f32x4{0,0,0,0}, f32x4{0,0,0,0}, f32x4{0,0,0,0}};
    f32x4 aB[3] = {f32x4{0,0,0,0}, f32x4{0,0,0,0}, f32x4{0,0,0,0}};
    float lp[3] = {0.f, 0.f, 0.f};
    int t0 = wid * TPW_;
    int t1 = min(t0 + TPW_, NTILE_);

    short4v kc = *reinterpret_cast<const short4v*>(Kp + (size_t)t0 * 256);
    short4v vc = *reinterpret_cast<const short4v*>(Vp + (size_t)t0 * 256);

    #pragma unroll 2
    for (int t = t0; t < t1; t++) {
        short4v kn = kc, vn = vc;
        if (t + 1 < t1) {
            kn = *reinterpret_cast<const short4v*>(Kp + (size_t)(t + 1) * 256);
            vn = *reinterpret_cast<const short4v*>(Vp + (size_t)(t + 1) * 256);
        }
        #pragma unroll
        for (int j = 0; j < 3; j++) {
            f32x4 s = __builtin_amdgcn_mfma_f32_16x16x16bf16_1k(kc, qf[j], f32x4{0,0,0,0}, 0, 0, 0);
            f32x4 p;
            short4v pbv;
            #pragma unroll
            for (int r = 0; r < 4; r++) {
                p[r] = __builtin_amdgcn_exp2f(s[r]);
                pbv[r] = (short)f2b(p[r]);
            }
            lp[j] += (p[0] + p[1]) + (p[2] + p[3]);
            if (t & 1) aB[j] = __builtin_amdgcn_mfma_f32_16x16x16bf16_1k(vc, pbv, aB[j], 0, 0, 0);
            else       aA[j] = __builtin_amdgcn_mfma_f32_16x16x16bf16_1k(vc, pbv, aA[j], 0, 0, 0);
        }
        kc = kn; vc = vn;
    }

    #pragma unroll
    for (int j = 0; j < 3; j++) {
        #pragma unroll
        for (int r = 0; r < 4; r++) red[wid][lane][j * 5 + r] = aA[j][r] + aB[j][r];
        red[wid][lane][j * 5 + 4] = lp[j];
    }
    __syncthreads();

    if (wid == 0) {
        float tot[15];
        #pragma unroll
        for (int j = 0; j < 15; j++)
            tot[j] = red[0][lane][j] + red[1][lane][j] + red[2][lane][j] + red[3][lane][j];
        int n = ng >> 2, g = ng & 3;
        #pragma unroll
        for (int j = 0; j < 3; j++) {
            float l = tot[j * 5 + 4] + __shfl_xor(tot[j * 5 + 4], 16);
            l += __shfl_xor(l, 32);
            l -= 28.f;             // pad keys contribute exp2(0)=1 each
            float inv = 1.f / l;
            short4v ov;
            #pragma unroll
            for (int r = 0; r < 4; r++) ov[r] = (short)f2b(tot[j * 5 + r] * inv);
            *reinterpret_cast<short4v*>(
                P.a_bt + ((size_t)n * 2304 + (qt0 + j) * 16 + l15) * 64 + g * HD_ + g4 * 4) = ov;
        }
    }
}

// ---------------------------------------------------------------------------
// S4: fused gate 1x1 MFMA + gpre + LSTM pointwise; 576 units = (nf, y, n).
// ---------------------------------------------------------------------------
__device__ void s4_gates(int bid, int tid, bool isbf, const MP& P) {
    int wid  = tid >> 6;
    int lane = tid & 63;
    int nf = bid % 3;
    int yn = bid / 3;
    int y = yn % 48;
    int n = yn / 48;
    int l15 = lane & 15;
    int kq  = lane >> 4;

    const unsigned short* Br = P.a_bt + ((size_t)n * 2304 + y * 48 + nf * 16 + l15) * 64;
    short8 b0 = *reinterpret_cast<const short8*>(Br + kq * 8);
    short8 b1 = *reinterpret_cast<const short8*>(Br + 32 + kq * 8);

    const unsigned short* wg = P.wt + WCONV_;
    f32x4 acc[4];
    #pragma unroll
    for (int g = 0; g < 4; g++) {
        const unsigned short* Ar = wg + (size_t)(g * 64 + wid * 16 + l15) * 64 + kq * 8;
        short8 a0 = *reinterpret_cast<const short8*>(Ar);
        short8 a1 = *reinterpret_cast<const short8*>(Ar + 32);
        f32x4 t = __builtin_amdgcn_mfma_f32_16x16x32_bf16(a0, b0, f32x4{0, 0, 0, 0}, 0, 0, 0);
        acc[g] = __builtin_amdgcn_mfma_f32_16x16x32_bf16(a1, b1, t, 0, 0, 0);
    }

    int p = y * 48 + nf * 16 + l15;
    int rbase = wid * 16 + kq * 4;
    #pragma unroll
    for (int reg = 0; reg < 4; reg++) {
        int r = rbase + reg;
        size_t crow = (size_t)n * CG_ + r;
        float ai = P.C[(crow)       * P_ + p] + acc[0][reg] + ldrt(P.bi, r, isbf);
        float af = P.C[(crow + 64)  * P_ + p] + acc[1][reg] + ldrt(P.bf, r, isbf);
        float ag = P.C[(crow + 128) * P_ + p] + acc[2][reg] + ldrt(P.bg, r, isbf);
        float ao = P.C[(crow + 192) * P_ + p] + acc[3][reg] + ldrt(P.bo, r, isbf);
        float ig = sigmoidf_(ai);
        float fg = sigmoidf_(af);
        float gg = tanh_fast(ag);
        float og = sigmoidf_(ao);
        size_t oidx = ((size_t)n * R_ + r) * P_ + p;
        float cn = fg * ldrt(P.c_in, oidx, isbf) + ig * gg;
        float hn = og * tanh_fast(cn);
        if (isbf) ((bf16*)P.h_out)[oidx] = __float2bfloat16(hn);
        else      ((float*)P.h_out)[oidx] = hn;
    }
}

// ---------------------------------------------------------------------------
// Plain kernels (no cooperative sync — grid.sync costs ~150us/sync on 8-XCD).
// ---------------------------------------------------------------------------
__global__ __launch_bounds__(256) void k_prep(MP P) {
    int gid = blockIdx.x * 256 + threadIdx.x;
    s1_all(gid, detect_bf(P.W_x), P);
}
__global__ __launch_bounds__(256) void k_conv(MP P) {
    __shared__ __align__(16) unsigned char smraw[150 * BROW_ * 2];   // 38.4 KB
    s2_conv(blockIdx.x, threadIdx.x, (unsigned short*)smraw, detect_bf(P.W_x), P);
}
__global__ __launch_bounds__(256) void k_attn(MP P) {
    __shared__ __align__(16) float red[4][64][15];
    s3_attn(blockIdx.x, threadIdx.x, red, P);
}
__global__ __launch_bounds__(256) void k_gates(MP P) {
    s4_gates(blockIdx.x, threadIdx.x, detect_bf(P.W_x), P);
}

// ---------------------------------------------------------------------------
extern "C" void kernel_launch(void* const* d_in, const int* in_sizes, int n_in,
                              void* d_out, int out_size, void* d_ws, size_t ws_size,
                              hipStream_t stream) {
    float* ws = (float*)d_ws;
    unsigned short* xh_t = (unsigned short*)(ws + 16);
    unsigned short* wt   = (unsigned short*)(ws + 16 + 640000);
    float* C = ws + 16 + 640000 + 266240;
    unsigned short* Qb = (unsigned short*)(C + (size_t)N_ * CG_ * P_);
    unsigned short* Kb = Qb + QTOT_;
    unsigned short* Vb = Kb + KTOT_;
    unsigned short* a_bt = Vb + VTOT_;

    MP mp;
    mp.x_in = d_in[0]; mp.h = d_in[1]; mp.c_in = d_in[2];
    mp.W_x = d_in[3];  mp.b_x = d_in[4]; mp.b_v = d_in[8];
    mp.bi = d_in[11]; mp.bf = d_in[14]; mp.bg = d_in[17]; mp.bo = d_in[20];
    mp.wsrc[0] = d_in[5];  mp.wsrc[1] = d_in[6];  mp.wsrc[2] = d_in[7];
    mp.wsrc[3] = d_in[10]; mp.wsrc[4] = d_in[13]; mp.wsrc[5] = d_in[16]; mp.wsrc[6] = d_in[19];
    mp.wsrc[7] = d_in[9];  mp.wsrc[8] = d_in[12]; mp.wsrc[9] = d_in[15]; mp.wsrc[10] = d_in[18];
    mp.xh_t = xh_t; mp.wt = wt; mp.Qb = Qb; mp.Kb = Kb; mp.Vb = Vb; mp.a_bt = a_bt;
    mp.C = C; mp.h_out = d_out;

    k_prep<<<768, 256, 0, stream>>>(mp);
    k_conv<<<768, 256, 0, stream>>>(mp);
    k_attn<<<768, 256, 0, stream>>>(mp);
    k_gates<<<576, 256, 0, stream>>>(mp);
}

// Round 20
// 79.458 us; speedup vs baseline: 1.0163x; 1.0163x over previous
//
#include <hip/hip_runtime.h>
#include <hip/hip_bf16.h>

typedef __hip_bfloat16 bf16;
typedef __attribute__((ext_vector_type(8))) short short8;
typedef __attribute__((ext_vector_type(4))) short short4v;
typedef __attribute__((ext_vector_type(4))) float f32x4;

#define N_      4
#define R_      64
#define HD_     16
#define H_      48
#define W_      48
#define P_      (H_ * W_)      // 2304
#define HP_     50
#define PP_     (HP_ * HP_)    // 2500
#define HK_     46
#define DK_     (HK_ * HK_)    // 2116
#define CG_     256
#define KPAD_   2144
#define WCONV_  516096
#define WGATE_  16384
#define NTILE_  134
#define TPW_    34
#define LOG2E_  1.44269504f
#define QTOT_   (16 * 2304 * 16)
#define KTOT_   (16 * KPAD_ * 16)
#define VTOT_   (16 * NTILE_ * 256)   // tile-blocked V: [ngi][tile][c][16]
#define GTH_    196608          // 768 * 256
#define ZXH_    (N_ * 196 * 16)
#define ZKB_    (16 * 28 * 2)
#define ZVB_    1024
#define ZTOT_   (ZXH_ + ZKB_ + ZVB_)
#define AWP_    18432           // wt shorts per (mg,wid): 9 taps * 4 cb * 512

// LDS B-tile: 150 rows x 128 shorts, XOR-swizzled (kept from r19: neutral
// but conflict-free + smaller than BPAD136).
#define BROW_   128
__device__ __forceinline__ int bswz(int row, int colshorts) {
    return row * BROW_ + (colshorts ^ ((row & 7) << 3));
}

__device__ __forceinline__ float sigmoidf_(float x) { return 1.f / (1.f + __expf(-x)); }
__device__ __forceinline__ float tanh_fast(float x) {
    float e = __expf(-2.f * fabsf(x));
    float t = (1.f - e) / (1.f + e);
    return copysignf(t, x);
}
__device__ __forceinline__ float ldrt(const void* p, size_t i, bool bf) {
    return bf ? __bfloat162float(((const bf16*)p)[i]) : ((const float*)p)[i];
}
__device__ __forceinline__ unsigned short f2b(float f) {
    bf16 b = __float2bfloat16(f);
    return *reinterpret_cast<unsigned short*>(&b);
}

struct MP {
    const void* x_in; const void* h; const void* c_in;
    const void* W_x;  const void* b_x; const void* b_v;
    const void* bi; const void* bf; const void* bg; const void* bo;
    const void* wsrc[11];
    unsigned short *xh_t, *wt, *Qb, *Kb, *Vb, *a_bt;
    float* C;
    void* h_out;
};

__device__ __forceinline__ bool detect_bf(const void* W_x) {
    const unsigned* wx = (const unsigned*)W_x;
    int votes = 0;
    #pragma unroll 8
    for (int i = 0; i < 64; i++) {
        unsigned e = (wx[i] >> 7) & 0xFFu;
        votes += (e >= 100u && e <= 134u) ? 1 : 0;
    }
    return votes >= 48;
}

// ---------------------------------------------------------------------------
// S1a: proj_x 1x1 conv (2 co x 2 p per item, 147456 items) -> xh_t bf16.
// ---------------------------------------------------------------------------
__device__ void s1_build_x(int idx, bool isbf, const MP& P) {
    int pp  = idx % 1152;
    int cog = (idx / 1152) & 31;
    int n   = idx / (1152 * 32);
    int p0 = pp * 2;
    int co0 = cog * 2;

    float acc[2][2];
    #pragma unroll
    for (int j = 0; j < 2; j++) { float b = ldrt(P.b_x, co0 + j, isbf); acc[j][0] = b; acc[j][1] = b; }

    if (isbf) {
        const unsigned* xw = (const unsigned*)P.x_in;
        const unsigned* ww = (const unsigned*)P.W_x;
        size_t xbase = ((size_t)n * 128 * P_ + p0) >> 1;
        #pragma unroll 4
        for (int ci = 0; ci < 128; ci += 2) {
            unsigned xa  = xw[xbase + (size_t)ci * (P_ / 2)];
            unsigned xb2 = xw[xbase + (size_t)(ci + 1) * (P_ / 2)];
            float x0a = __uint_as_float(xa << 16),  x1a = __uint_as_float(xa & 0xffff0000u);
            float x0b = __uint_as_float(xb2 << 16), x1b = __uint_as_float(xb2 & 0xffff0000u);
            #pragma unroll
            for (int j = 0; j < 2; j++) {
                unsigned wp2 = ww[((co0 + j) * 128 + ci) >> 1];
                float w0 = __uint_as_float(wp2 << 16);
                float w1 = __uint_as_float(wp2 & 0xffff0000u);
                acc[j][0] += w0 * x0a + w1 * x0b;
                acc[j][1] += w0 * x1a + w1 * x1b;
            }
        }
    } else {
        const float* xf = (const float*)P.x_in;
        const float* wf = (const float*)P.W_x;
        size_t xb = (size_t)n * 128 * P_ + p0;
        #pragma unroll 4
        for (int ci = 0; ci < 128; ci++) {
            float x0 = xf[xb + (size_t)ci * P_];
            float x1 = xf[xb + (size_t)ci * P_ + 1];
            #pragma unroll
            for (int j = 0; j < 2; j++) {
                float w = wf[(co0 + j) * 128 + ci];
                acc[j][0] += w * x0;
                acc[j][1] += w * x1;
            }
        }
    }
    #pragma unroll
    for (int pi = 0; pi < 2; pi++) {
        int p = p0 + pi;
        int py = p / W_ + 1, px = p % W_ + 1;
        unsigned pk = (unsigned)f2b(acc[0][pi]) | ((unsigned)f2b(acc[1][pi]) << 16);
        *reinterpret_cast<unsigned*>(P.xh_t + ((size_t)n * PP_ + py * HP_ + px) * 128 + co0) = pk;
    }
}

// S1b: h -> xh_t channels 64..127 (8 ch x 2 px per item, 36864 items).
__device__ void s1_copy_h(int idx, bool isbf, const MP& P) {
    int pp = idx % 1152;
    int cgp = (idx / 1152) & 7;
    int n  = idx / (1152 * 8);
    int p0 = pp * 2;
    int py = p0 / W_ + 1, px = p0 % W_ + 1;
    short8 v0, v1;
    if (isbf) {
        const unsigned* hw = (const unsigned*)P.h;
        #pragma unroll
        for (int j = 0; j < 8; j++) {
            unsigned pr = hw[(((size_t)n * R_ + cgp * 8 + j) * P_ + p0) >> 1];
            v0[j] = (short)(pr & 0xffffu);
            v1[j] = (short)(pr >> 16);
        }
    } else {
        #pragma unroll
        for (int j = 0; j < 8; j++) {
            size_t b = ((size_t)n * R_ + cgp * 8 + j) * P_ + p0;
            v0[j] = (short)f2b(ldrt(P.h, b, false));
            v1[j] = (short)f2b(ldrt(P.h, b + 1, false));
        }
    }
    unsigned short* dst = P.xh_t + ((size_t)n * PP_ + py * HP_ + px) * 128 + 64 + cgp * 8;
    *reinterpret_cast<short8*>(dst) = v0;
    *reinterpret_cast<short8*>(dst + 128) = v1;
}

// S1c: weight repack (fragment-major conv region — r17 win).
__device__ void s1_wt(int idx, bool isbf, const MP& P) {
    if (idx < WCONV_) {
        int j   = idx & 7;
        int kq  = (idx >> 3) & 3;
        int l15 = (idx >> 5) & 15;
        int cb  = (idx >> 9) & 3;
        int tap = (idx >> 11) % 9;
        int wp  = idx / AWP_;
        int mg  = wp >> 2, wid = wp & 3;
        int co  = wid * 16 + l15;
        int ci  = cb * 32 + kq * 8 + j;
        P.wt[idx] = f2b(ldrt(P.wsrc[mg], (size_t)(co * 128 + ci) * 9 + tap, isbf));
    } else if (idx < WCONV_ + WGATE_) {
        int j  = idx - WCONV_;
        int ca = j & 63;
        int m  = j >> 6;
        int gate = m >> 6, r = m & 63;
        P.wt[idx] = f2b(ldrt(P.wsrc[7 + gate], r * 64 + ca, isbf));
    }
}

// S1d: zero pad item.
__device__ void s1_zero(int idx, const MP& P) {
    const short8 z8 = {0, 0, 0, 0, 0, 0, 0, 0};
    if (idx < ZXH_) {
        int cig = idx & 15;
        int pi  = (idx >> 4) % 196;
        int n   = idx / (196 * 16);
        int pp;
        if (pi < 50)       pp = pi;
        else if (pi < 100) pp = 49 * 50 + (pi - 50);
        else if (pi < 148) pp = (pi - 100 + 1) * 50;
        else               pp = (pi - 148 + 1) * 50 + 49;
        *reinterpret_cast<short8*>(P.xh_t + ((size_t)n * PP_ + pp) * 128 + cig * 8) = z8;
        return;
    }
    int j = idx - ZXH_;
    if (j < ZKB_) {
        int hh  = j & 1;
        int key = ((j >> 1) % 28) + DK_;
        int ngi = j / (28 * 2);
        *reinterpret_cast<short8*>(P.Kb + ((size_t)ngi * KPAD_ + key) * 16 + hh * 8) = z8;
        return;
    }
    j -= ZKB_;
    if (j < ZVB_) {
        int h8  = j & 1;
        int c   = (j >> 1) & 15;
        int tl  = (j >> 5) & 1;
        int ngi = j >> 6;
        *reinterpret_cast<short8*>(
            P.Vb + (((size_t)ngi * NTILE_ + 132 + tl) * 16 + c) * 16 + h8 * 8) = z8;
    }
}

__device__ void s1_all(int gid, bool isbf, const MP& P) {
    if (gid < 147456) s1_build_x(gid, isbf, P);
    if (gid < 36864)  s1_copy_h(gid, isbf, P);
    for (int i = gid; i < WCONV_ + WGATE_; i += GTH_) s1_wt(i, isbf, P);
    if (gid < ZTOT_)  s1_zero(gid, P);
}

// ---------------------------------------------------------------------------
// S2: seven 3x3 convs as one implicit GEMM; T5 setprio around MFMA cluster.
// ---------------------------------------------------------------------------
__device__ void s2_conv(int bid, int tid, unsigned short* Bs, bool isbf, const MP& P) {
    int wid  = tid >> 6;
    int lane = tid & 63;
    int pb = bid & 3;
    int y  = (bid >> 2) % 48;
    int n  = bid / 192;
    int l15 = lane & 15;
    int kq  = lane >> 4;

    const unsigned short* src = P.xh_t + (size_t)n * PP_ * 128 + (size_t)y * HP_ * 128;
    for (int i = tid; i < 2400; i += 256) {
        int r  = i / 800, e8 = i % 800;
        int px = e8 >> 4, cig = e8 & 15;
        int row = r * HP_ + px;
        short8 v = *reinterpret_cast<const short8*>(src + r * 6400 + e8 * 8);
        *reinterpret_cast<short8*>(Bs + bswz(row, cig * 8)) = v;
    }
    __syncthreads();

    int mg0 = pb * 2;
    int mg1 = min(pb * 2 + 1, 6);
    int lofs = (l15 * 4 + kq) * 8;
    const unsigned short* Ab0 = P.wt + (size_t)(mg0 * 4 + wid) * AWP_ + lofs;
    const unsigned short* Ab1 = P.wt + (size_t)(mg1 * 4 + wid) * AWP_ + lofs;

    f32x4 acc[2][3] = {{f32x4{0,0,0,0}, f32x4{0,0,0,0}, f32x4{0,0,0,0}},
                       {f32x4{0,0,0,0}, f32x4{0,0,0,0}, f32x4{0,0,0,0}}};

    short8 Acur[2][4], Anext[2][4];
    #pragma unroll
    for (int cb = 0; cb < 4; cb++) {
        Acur[0][cb] = *reinterpret_cast<const short8*>(Ab0 + cb * 512);
        Acur[1][cb] = *reinterpret_cast<const short8*>(Ab1 + cb * 512);
    }

    #pragma unroll
    for (int tap = 0; tap < 9; tap++) {
        if (tap < 8) {
            #pragma unroll
            for (int cb = 0; cb < 4; cb++) {
                Anext[0][cb] = *reinterpret_cast<const short8*>(Ab0 + (tap + 1) * 2048 + cb * 512);
                Anext[1][cb] = *reinterpret_cast<const short8*>(Ab1 + (tap + 1) * 2048 + cb * 512);
            }
        }
        int r = tap / 3, c = tap % 3;
        #pragma unroll
        for (int cb = 0; cb < 4; cb++) {
            short8 b8[3];
            #pragma unroll
            for (int nf = 0; nf < 3; nf++) {
                int row = r * HP_ + c + nf * 16 + l15;
                b8[nf] = *reinterpret_cast<const short8*>(
                    Bs + bswz(row, cb * 32 + kq * 8));
            }
            __builtin_amdgcn_s_setprio(1);
            #pragma unroll
            for (int nf = 0; nf < 3; nf++) {
                acc[0][nf] = __builtin_amdgcn_mfma_f32_16x16x32_bf16(Acur[0][cb], b8[nf], acc[0][nf], 0, 0, 0);
                acc[1][nf] = __builtin_amdgcn_mfma_f32_16x16x32_bf16(Acur[1][cb], b8[nf], acc[1][nf], 0, 0, 0);
            }
            __builtin_amdgcn_s_setprio(0);
        }
        #pragma unroll
        for (int cb = 0; cb < 4; cb++) {
            Acur[0][cb] = Anext[0][cb];
            Acur[1][cb] = Anext[1][cb];
        }
    }

    #pragma unroll
    for (int f = 0; f < 2; f++) {
        if (pb == 3 && f == 1) break;
        int mg = pb * 2 + f;
        if (mg >= 3) {
            #pragma unroll
            for (int nf = 0; nf < 3; nf++) {
                int p = y * 48 + nf * 16 + l15;
                #pragma unroll
                for (int reg = 0; reg < 4; reg++) {
                    int row = (mg - 3) * 64 + wid * 16 + kq * 4 + reg;
                    P.C[((size_t)n * CG_ + row) * P_ + p] = acc[f][nf][reg];
                }
            }
        } else {
            int g = wid;
            int ngi = n * 4 + g;
            #pragma unroll
            for (int nf = 0; nf < 3; nf++) {
                int x = nf * 16 + l15;
                int p = y * 48 + x;
                if (mg == 0) {
                    short4v q4;
                    #pragma unroll
                    for (int reg = 0; reg < 4; reg++) q4[reg] = (short)f2b(acc[f][nf][reg] * LOG2E_);
                    *reinterpret_cast<short4v*>(P.Qb + ((size_t)ngi * 2304 + p) * 16 + kq * 4) = q4;
                } else if ((unsigned)(x - 1) < 46u && (unsigned)(y - 1) < 46u) {
                    int key = (y - 1) * 46 + (x - 1);
                    if (mg == 1) {
                        short4v k4;
                        #pragma unroll
                        for (int reg = 0; reg < 4; reg++) k4[reg] = (short)f2b(acc[f][nf][reg]);
                        *reinterpret_cast<short4v*>(P.Kb + ((size_t)ngi * KPAD_ + key) * 16 + kq * 4) = k4;
                    } else {
                        int tile = key >> 4, kw = key & 15;
                        #pragma unroll
                        for (int reg = 0; reg < 4; reg++) {
                            int c2 = kq * 4 + reg;
                            P.Vb[(((size_t)ngi * NTILE_ + tile) * 16 + c2) * 16 + kw] =
                                f2b(acc[f][nf][reg] + ldrt(P.b_v, g * 16 + c2, isbf));
                        }
                    }
                }
            }
        }
    }
}

// ---------------------------------------------------------------------------
// S3: MFMA flash attention; T5 setprio around per-tile compute body.
// ---------------------------------------------------------------------------
__device__ void s3_attn(int bid, int tid, float (*red)[64][15], const MP& P) {
    int wid  = tid >> 6;
    int lane = tid & 63;
    int ng = bid & 15;
    int q3 = bid >> 4;
    int qt0 = q3 * 3;
    int l15 = lane & 15;
    int g4  = lane >> 4;

    short4v qf[3];
    #pragma unroll
    for (int j = 0; j < 3; j++)
        qf[j] = *reinterpret_cast<const short4v*>(
            P.Qb + ((size_t)ng * 2304 + (qt0 + j) * 16 + l15) * 16 + g4 * 4);
    const unsigned short* Kp = P.Kb + ((size_t)ng * KPAD_ + l15) * 16 + g4 * 4;
    const unsigned short* Vp = P.Vb + (size_t)ng * NTILE_ * 256 + l15 * 16 + g4 * 4;

    f32x4 aA[3] = {f32x4{0,0,0,0}, f32x4{0,0,0,0}, f32x4{0,0,0,0}};
    f32x4 aB[3] = {f32x4{0,0,0,0}, f32x4{0,0,0,0}, f32x4{0,0,0,0}};
    float lp[3] = {0.f, 0.f, 0.f};
    int t0 = wid * TPW_;
    int t1 = min(t0 + TPW_, NTILE_);

    short4v kc = *reinterpret_cast<const short4v*>(Kp + (size_t)t0 * 256);
    short4v vc = *reinterpret_cast<const short4v*>(Vp + (size_t)t0 * 256);

    #pragma unroll 2
    for (int t = t0; t < t1; t++) {
        short4v kn = kc, vn = vc;
        if (t + 1 < t1) {
            kn = *reinterpret_cast<const short4v*>(Kp + (size_t)(t + 1) * 256);
            vn = *reinterpret_cast<const short4v*>(Vp + (size_t)(t + 1) * 256);
        }
        __builtin_amdgcn_s_setprio(1);
        #pragma unroll
        for (int j = 0; j < 3; j++) {
            f32x4 s = __builtin_amdgcn_mfma_f32_16x16x16bf16_1k(kc, qf[j], f32x4{0,0,0,0}, 0, 0, 0);
            f32x4 p;
            short4v pbv;
            #pragma unroll
            for (int r = 0; r < 4; r++) {
                p[r] = __builtin_amdgcn_exp2f(s[r]);
                pbv[r] = (short)f2b(p[r]);
            }
            lp[j] += (p[0] + p[1]) + (p[2] + p[3]);
            if (t & 1) aB[j] = __builtin_amdgcn_mfma_f32_16x16x16bf16_1k(vc, pbv, aB[j], 0, 0, 0);
            else       aA[j] = __builtin_amdgcn_mfma_f32_16x16x16bf16_1k(vc, pbv, aA[j], 0, 0, 0);
        }
        __builtin_amdgcn_s_setprio(0);
        kc = kn; vc = vn;
    }

    #pragma unroll
    for (int j = 0; j < 3; j++) {
        #pragma unroll
        for (int r = 0; r < 4; r++) red[wid][lane][j * 5 + r] = aA[j][r] + aB[j][r];
        red[wid][lane][j * 5 + 4] = lp[j];
    }
    __syncthreads();

    if (wid == 0) {
        float tot[15];
        #pragma unroll
        for (int j = 0; j < 15; j++)
            tot[j] = red[0][lane][j] + red[1][lane][j] + red[2][lane][j] + red[3][lane][j];
        int n = ng >> 2, g = ng & 3;
        #pragma unroll
        for (int j = 0; j < 3; j++) {
            float l = tot[j * 5 + 4] + __shfl_xor(tot[j * 5 + 4], 16);
            l += __shfl_xor(l, 32);
            l -= 28.f;             // pad keys contribute exp2(0)=1 each
            float inv = 1.f / l;
            short4v ov;
            #pragma unroll
            for (int r = 0; r < 4; r++) ov[r] = (short)f2b(tot[j * 5 + r] * inv);
            *reinterpret_cast<short4v*>(
                P.a_bt + ((size_t)n * 2304 + (qt0 + j) * 16 + l15) * 64 + g * HD_ + g4 * 4) = ov;
        }
    }
}

// ---------------------------------------------------------------------------
// S4: fused gate 1x1 MFMA + gpre + LSTM pointwise; 576 units = (nf, y, n).
// ---------------------------------------------------------------------------
__device__ void s4_gates(int bid, int tid, bool isbf, const MP& P) {
    int wid  = tid >> 6;
    int lane = tid & 63;
    int nf = bid % 3;
    int yn = bid / 3;
    int y = yn % 48;
    int n = yn / 48;
    int l15 = lane & 15;
    int kq  = lane >> 4;

    const unsigned short* Br = P.a_bt + ((size_t)n * 2304 + y * 48 + nf * 16 + l15) * 64;
    short8 b0 = *reinterpret_cast<const short8*>(Br + kq * 8);
    short8 b1 = *reinterpret_cast<const short8*>(Br + 32 + kq * 8);

    const unsigned short* wg = P.wt + WCONV_;
    f32x4 acc[4];
    #pragma unroll
    for (int g = 0; g < 4; g++) {
        const unsigned short* Ar = wg + (size_t)(g * 64 + wid * 16 + l15) * 64 + kq * 8;
        short8 a0 = *reinterpret_cast<const short8*>(Ar);
        short8 a1 = *reinterpret_cast<const short8*>(Ar + 32);
        f32x4 t = __builtin_amdgcn_mfma_f32_16x16x32_bf16(a0, b0, f32x4{0, 0, 0, 0}, 0, 0, 0);
        acc[g] = __builtin_amdgcn_mfma_f32_16x16x32_bf16(a1, b1, t, 0, 0, 0);
    }

    int p = y * 48 + nf * 16 + l15;
    int rbase = wid * 16 + kq * 4;
    #pragma unroll
    for (int reg = 0; reg < 4; reg++) {
        int r = rbase + reg;
        size_t crow = (size_t)n * CG_ + r;
        float ai = P.C[(crow)       * P_ + p] + acc[0][reg] + ldrt(P.bi, r, isbf);
        float af = P.C[(crow + 64)  * P_ + p] + acc[1][reg] + ldrt(P.bf, r, isbf);
        float ag = P.C[(crow + 128) * P_ + p] + acc[2][reg] + ldrt(P.bg, r, isbf);
        float ao = P.C[(crow + 192) * P_ + p] + acc[3][reg] + ldrt(P.bo, r, isbf);
        float ig = sigmoidf_(ai);
        float fg = sigmoidf_(af);
        float gg = tanh_fast(ag);
        float og = sigmoidf_(ao);
        size_t oidx = ((size_t)n * R_ + r) * P_ + p;
        float cn = fg * ldrt(P.c_in, oidx, isbf) + ig * gg;
        float hn = og * tanh_fast(cn);
        if (isbf) ((bf16*)P.h_out)[oidx] = __float2bfloat16(hn);
        else      ((float*)P.h_out)[oidx] = hn;
    }
}

// ---------------------------------------------------------------------------
__global__ __launch_bounds__(256) void k_prep(MP P) {
    int gid = blockIdx.x * 256 + threadIdx.x;
    s1_all(gid, detect_bf(P.W_x), P);
}
__global__ __launch_bounds__(256) void k_conv(MP P) {
    __shared__ __align__(16) unsigned char smraw[150 * BROW_ * 2];   // 38.4 KB
    s2_conv(blockIdx.x, threadIdx.x, (unsigned short*)smraw, detect_bf(P.W_x), P);
}
__global__ __launch_bounds__(256) void k_attn(MP P) {
    __shared__ __align__(16) float red[4][64][15];
    s3_attn(blockIdx.x, threadIdx.x, red, P);
}
__global__ __launch_bounds__(256) void k_gates(MP P) {
    s4_gates(blockIdx.x, threadIdx.x, detect_bf(P.W_x), P);
}

// ---------------------------------------------------------------------------
extern "C" void kernel_launch(void* const* d_in, const int* in_sizes, int n_in,
                              void* d_out, int out_size, void* d_ws, size_t ws_size,
                              hipStream_t stream) {
    float* ws = (float*)d_ws;
    unsigned short* xh_t = (unsigned short*)(ws + 16);
    unsigned short* wt   = (unsigned short*)(ws + 16 + 640000);
    float* C = ws + 16 + 640000 + 266240;
    unsigned short* Qb = (unsigned short*)(C + (size_t)N_ * CG_ * P_);
    unsigned short* Kb = Qb + QTOT_;
    unsigned short* Vb = Kb + KTOT_;
    unsigned short* a_bt = Vb + VTOT_;

    MP mp;
    mp.x_in = d_in[0]; mp.h = d_in[1]; mp.c_in = d_in[2];
    mp.W_x = d_in[3];  mp.b_x = d_in[4]; mp.b_v = d_in[8];
    mp.bi = d_in[11]; mp.bf = d_in[14]; mp.bg = d_in[17]; mp.bo = d_in[20];
    mp.wsrc[0] = d_in[5];  mp.wsrc[1] = d_in[6];  mp.wsrc[2] = d_in[7];
    mp.wsrc[3] = d_in[10]; mp.wsrc[4] = d_in[13]; mp.wsrc[5] = d_in[16]; mp.wsrc[6] = d_in[19];
    mp.wsrc[7] = d_in[9];  mp.wsrc[8] = d_in[12]; mp.wsrc[9] = d_in[15]; mp.wsrc[10] = d_in[18];
    mp.xh_t = xh_t; mp.wt = wt; mp.Qb = Qb; mp.Kb = Kb; mp.Vb = Vb; mp.a_bt = a_bt;
    mp.C = C; mp.h_out = d_out;

    k_prep<<<768, 256, 0, stream>>>(mp);
    k_conv<<<768, 256, 0, stream>>>(mp);
    k_attn<<<768, 256, 0, stream>>>(mp);
    k_gates<<<576, 256, 0, stream>>>(mp);
}